// Round 1
// baseline (50292.612 us; speedup 1.0000x reference)
//
#include <hip/hip_runtime.h>
#include <math.h>

#define N_ST 512
#define N_CT 128
#define DIM  640
#define T_H  256
#define LTRI 8256   /* 128*129/2 */

typedef __attribute__((ext_vector_type(8))) short bf16x8;
typedef __attribute__((ext_vector_type(4))) float f32x4;

__device__ __forceinline__ ushort f2bf(float x) {
  unsigned u = __float_as_uint(x);
  unsigned r = (u + 0x7fffu + ((u >> 16) & 1u)) >> 16;
  return (ushort)r;
}
__device__ __forceinline__ float bf2f(ushort h) {
  return __uint_as_float(((unsigned)h) << 16);
}

__device__ __forceinline__ void tri_decode(int b, int& r, int& c) {
  int rr = (int)((sqrtf(8.0f * b + 1.0f) - 1.0f) * 0.5f);
  while ((rr + 1) * (rr + 2) / 2 <= b) rr++;
  while (rr * (rr + 1) / 2 > b) rr--;
  r = rr; c = b - rr * (rr + 1) / 2;
}

// ---------------------------------------------------------------------------
// Shared split-bf16 MFMA tile core, "NT": acc[i,j] += sum_k A[i,k]*B[j,k]
// Tile 64x64, 4 waves (2x2), each wave 32x32 (2x2 of 16x16x32 MFMA).
// ---------------------------------------------------------------------------
__device__ __forceinline__ void gemm_core(
    const ushort* __restrict__ Ah, const ushort* __restrict__ Al, int lda,
    const ushort* __restrict__ Bh, const ushort* __restrict__ Bl, int ldb,
    int i0, int j0, int K,
    ushort* __restrict__ As_h, ushort* __restrict__ As_l,
    ushort* __restrict__ Bs_h, ushort* __restrict__ Bs_l,
    f32x4 (&acc)[2][2])
{
  const int tid = threadIdx.x;
  const int wid = tid >> 6, lane = tid & 63;
  const int wm = (wid & 1) * 32, wn = (wid >> 1) * 32;
  const int fr = lane & 15, fq = lane >> 4;

#pragma unroll
  for (int ai = 0; ai < 2; ai++)
#pragma unroll
    for (int bj = 0; bj < 2; bj++) acc[ai][bj] = (f32x4){0.f, 0.f, 0.f, 0.f};

  for (int k0 = 0; k0 < K; k0 += 64) {
#pragma unroll
    for (int h = 0; h < 2; h++) {
      int cch = tid + h * 256;             // 512 chunks of 16B per array
      int row = cch >> 3, col = (cch & 7) << 3;
      *(uint4*)&As_h[row*72 + col] = *(const uint4*)&Ah[(size_t)(i0+row)*lda + k0 + col];
      *(uint4*)&As_l[row*72 + col] = *(const uint4*)&Al[(size_t)(i0+row)*lda + k0 + col];
      *(uint4*)&Bs_h[row*72 + col] = *(const uint4*)&Bh[(size_t)(j0+row)*ldb + k0 + col];
      *(uint4*)&Bs_l[row*72 + col] = *(const uint4*)&Bl[(size_t)(j0+row)*ldb + k0 + col];
    }
    __syncthreads();
#pragma unroll
    for (int kc = 0; kc < 64; kc += 32) {
      bf16x8 ah[2], al[2], bh[2], bl[2];
#pragma unroll
      for (int t = 0; t < 2; t++) {
        ah[t] = *(bf16x8*)&As_h[(wm + t*16 + fr)*72 + kc + fq*8];
        al[t] = *(bf16x8*)&As_l[(wm + t*16 + fr)*72 + kc + fq*8];
        bh[t] = *(bf16x8*)&Bs_h[(wn + t*16 + fr)*72 + kc + fq*8];
        bl[t] = *(bf16x8*)&Bs_l[(wn + t*16 + fr)*72 + kc + fq*8];
      }
#pragma unroll
      for (int tm = 0; tm < 2; tm++)
#pragma unroll
        for (int tn = 0; tn < 2; tn++) {
          acc[tm][tn] = __builtin_amdgcn_mfma_f32_16x16x32_bf16(ah[tm], bh[tn], acc[tm][tn], 0, 0, 0);
          acc[tm][tn] = __builtin_amdgcn_mfma_f32_16x16x32_bf16(ah[tm], bl[tn], acc[tm][tn], 0, 0, 0);
          acc[tm][tn] = __builtin_amdgcn_mfma_f32_16x16x32_bf16(al[tm], bh[tn], acc[tm][tn], 0, 0, 0);
        }
    }
    __syncthreads();
  }
}

// ---------------------------------------------------------------------------
// 128x128 Cholesky of Quu (lower-packed) with 256 threads, Sp/dinv in LDS.
// ---------------------------------------------------------------------------
__device__ __forceinline__ void chol128_256(
    const float* __restrict__ Qm, float* __restrict__ Lout,
    float* __restrict__ invd_g, float* __restrict__ Sp, float* __restrict__ dinv)
{
  const int tid = threadIdx.x;
  for (int idx = tid; idx < LTRI; idx += 256) {
    int r, c; tri_decode(idx, r, c);
    Sp[idx] = Qm[(size_t)(N_ST + r)*DIM + N_ST + c];
  }
  __syncthreads();

  for (int p = 0; p < 128; p += 16) {
    if (tid < 64) {
      const int t = tid;
      const int toff = (p + t)*(p + t + 1)/2;
      float a[16];
#pragma unroll
      for (int c2 = 0; c2 < 16; c2++)
        a[c2] = (t < 16 && c2 <= t) ? Sp[toff + p + c2] : 0.0f;
      float Lr[16];
      float myinv = 0.0f;
#pragma unroll
      for (int j = 0; j < 16; j++) {
        float dj  = __shfl(a[j], j);
        float sq  = sqrtf(dj);
        float inv = 1.0f / sq;
        float Ltj = (t == j) ? sq : a[j] * inv;
#pragma unroll
        for (int jp = j + 1; jp < 16; jp++) {
          float Lpj = __shfl(Ltj, jp);
          a[jp] -= Ltj * Lpj;
        }
        Lr[j] = Ltj;
        if (t == j) myinv = inv;
      }
      if (t < 16) {
#pragma unroll
        for (int j = 0; j < 16; j++)
          if (j <= t) Sp[toff + p + j] = Lr[j];
        dinv[p + t] = myinv;
      }
    }
    __syncthreads();

    {
      int r = p + 16 + tid;
      if (r < 128) {
        const int roff = r*(r+1)/2;
        float Lrow[16];
#pragma unroll
        for (int jj = 0; jj < 16; jj++) {
          float accv = Sp[roff + p + jj];
          const int doff = (p + jj)*(p + jj + 1)/2;
#pragma unroll
          for (int t2 = 0; t2 < 16; t2++)
            if (t2 < jj) accv -= Lrow[t2] * Sp[doff + p + t2];
          Lrow[jj] = accv * dinv[p + jj];
        }
#pragma unroll
        for (int jj = 0; jj < 16; jj++) Sp[roff + p + jj] = Lrow[jj];
      }
    }
    __syncthreads();

    {
      int nR = 112 - p;
      if (nR > 0) {
        int nq = nR >> 2;
        int pairs = nq * (nq + 1) / 2;
        for (int e = tid; e < pairs; e += 256) {
          int ri, ci; tri_decode(e, ri, ci);
          int r0 = p + 16 + ri*4;
          int c0 = p + 16 + ci*4;
          bool dg = (ri == ci);
          int ro[4], co[4];
#pragma unroll
          for (int i2 = 0; i2 < 4; i2++) ro[i2] = (r0+i2)*(r0+i2+1)/2;
#pragma unroll
          for (int j2 = 0; j2 < 4; j2++) co[j2] = (c0+j2)*(c0+j2+1)/2;
          float acc[4][4];
#pragma unroll
          for (int i2 = 0; i2 < 4; i2++)
#pragma unroll
            for (int j2 = 0; j2 < 4; j2++)
              acc[i2][j2] = (!dg || (c0+j2) <= (r0+i2)) ? Sp[ro[i2] + c0 + j2] : 0.0f;
#pragma unroll
          for (int t2 = 0; t2 < 16; t2++) {
            float rv[4], cv2[4];
#pragma unroll
            for (int i2 = 0; i2 < 4; i2++) rv[i2]  = Sp[ro[i2] + p + t2];
#pragma unroll
            for (int j2 = 0; j2 < 4; j2++) cv2[j2] = Sp[co[j2] + p + t2];
#pragma unroll
            for (int i2 = 0; i2 < 4; i2++)
#pragma unroll
              for (int j2 = 0; j2 < 4; j2++)
                acc[i2][j2] -= rv[i2] * cv2[j2];
          }
#pragma unroll
          for (int i2 = 0; i2 < 4; i2++)
#pragma unroll
            for (int j2 = 0; j2 < 4; j2++)
              if (!dg || (c0+j2) <= (r0+i2)) Sp[ro[i2] + c0 + j2] = acc[i2][j2];
        }
      }
    }
    __syncthreads();
  }

  for (int idx = tid; idx < LTRI; idx += 256) Lout[idx] = Sp[idx];
  if (tid < 128) invd_g[tid] = dinv[tid];
}

// ---------------------------------------------------------------------------
// Kernel 1: FV = F^T V (80 gemm blocks) + aux block 80: Vf = V@f, fv = f.v
// ---------------------------------------------------------------------------
__global__ __launch_bounds__(256) void gemm_fv_kernel(
    const ushort* __restrict__ FTh, const ushort* __restrict__ FTl,
    const ushort* __restrict__ Vh, const ushort* __restrict__ Vl,
    float* __restrict__ FV, ushort* __restrict__ FVh, ushort* __restrict__ FVl,
    const float* __restrict__ Vin, int ldV, const float* __restrict__ vin,
    const float* __restrict__ f, float* __restrict__ Vf, float* __restrict__ fv)
{
  __shared__ ushort As_h[64*72], As_l[64*72], Bs_h[64*72], Bs_l[64*72];
  __shared__ float red[256];
  const int b = blockIdx.x, tid = threadIdx.x;

  if (b < 80) {
    const int i0 = (b % 10) * 64, j0 = (b / 10) * 64;
    f32x4 acc[2][2];
    gemm_core(FTh, FTl, N_ST, Vh, Vl, N_ST, i0, j0, N_ST,
              As_h, As_l, Bs_h, Bs_l, acc);
    const int wid = tid >> 6, lane = tid & 63;
    const int wm = (wid & 1)*32, wn = (wid >> 1)*32;
    const int fr = lane & 15, fq = lane >> 4;
#pragma unroll
    for (int tm = 0; tm < 2; tm++)
#pragma unroll
      for (int tn = 0; tn < 2; tn++)
#pragma unroll
        for (int r = 0; r < 4; r++) {
          int i = i0 + wm + tm*16 + fq*4 + r;
          int j = j0 + wn + tn*16 + fr;
          float v = acc[tm][tn][r];
          size_t o = (size_t)i * N_ST + j;
          FV[o] = v;
          ushort h = f2bf(v);
          FVh[o] = h;
          FVl[o] = f2bf(v - bf2f(h));
        }
  } else {
    // aux: Vf = Vin @ f ; fv = f . vin
#pragma unroll
    for (int rr = 0; rr < 2; rr++) {
      int i = tid + rr*256;
      const float4* vr = (const float4*)(Vin + (size_t)i * ldV);
      const float4* f4 = (const float4*)f;
      float a4 = 0.0f;
      for (int kk = 0; kk < N_ST/4; kk++) {
        float4 x = vr[kk], y = f4[kk];
        a4 += x.x*y.x + x.y*y.y + x.z*y.z + x.w*y.w;
      }
      Vf[i] = a4;
    }
    float pv = f[tid]*vin[tid] + f[tid+256]*vin[tid+256];
    red[tid] = pv;
    __syncthreads();
    for (int s2 = 128; s2 > 0; s2 >>= 1) {
      if (tid < s2) red[tid] += red[tid + s2];
      __syncthreads();
    }
    if (tid == 0) *fv = red[0];
  }
}

// ---------------------------------------------------------------------------
// Kernel 2: Q = C + FV F, lower-triangle tiles only (55 blocks) + mirror
//   store; last-finishing Quu tile runs the 128x128 Cholesky in its tail.
//   Blocks 55..57: q = c + FV@f + F^T@v.
// ---------------------------------------------------------------------------
__global__ __launch_bounds__(256) void gemm_q_kernel(
    const ushort* __restrict__ FVh, const ushort* __restrict__ FVl,
    const ushort* __restrict__ FTh, const ushort* __restrict__ FTl,
    const float* __restrict__ Cm, float* __restrict__ Qm,
    const float* __restrict__ FV, const float* __restrict__ F,
    const float* __restrict__ f, const float* __restrict__ cvec,
    const float* __restrict__ vin,
    float* __restrict__ qv, float* __restrict__ Lw, float* __restrict__ invd_g,
    unsigned* __restrict__ cnt, int step)
{
  union Sm {
    struct { ushort Ah[64*72], Al[64*72], Bh[64*72], Bl[64*72]; } g;
    struct { float Sp[LTRI]; float dinv[128]; } c;
  };
  __shared__ Sm sm;
  __shared__ int lastFlag;
  const int b = blockIdx.x, tid = threadIdx.x;

  if (b < 55) {
    int bi, bj; tri_decode(b, bi, bj);      // bi >= bj, 10x10 lower
    const int i0 = bi * 64, j0 = bj * 64;
    f32x4 acc[2][2];
    gemm_core(FVh, FVl, N_ST, FTh, FTl, N_ST, i0, j0, N_ST,
              sm.g.Ah, sm.g.Al, sm.g.Bh, sm.g.Bl, acc);
    const int wid = tid >> 6, lane = tid & 63;
    const int wm = (wid & 1)*32, wn = (wid >> 1)*32;
    const int fr = lane & 15, fq = lane >> 4;
#pragma unroll
    for (int tm = 0; tm < 2; tm++)
#pragma unroll
      for (int tn = 0; tn < 2; tn++)
#pragma unroll
        for (int r = 0; r < 4; r++) {
          int i = i0 + wm + tm*16 + fq*4 + r;
          int j = j0 + wn + tn*16 + fr;
          float v = acc[tm][tn][r] + Cm[(size_t)i*DIM + j];
          Qm[(size_t)i*DIM + j] = v;
          if (bi != bj) Qm[(size_t)j*DIM + i] = v;   // exact mirror (Q symmetric)
        }
    // The 3 tiles covering Quu (bj >= 8 implies bi >= 8): counter; last does chol.
    if (bj >= 8) {
      __syncthreads();
      if (tid == 0) {
        __threadfence();
        unsigned old = atomicAdd(cnt, 1u);
        lastFlag = (old == 3u*(unsigned)step + 2u) ? 1 : 0;
      }
      __syncthreads();
      if (lastFlag) {
        __threadfence();
        chol128_256(Qm, Lw, invd_g, sm.c.Sp, sm.c.dinv);
      }
    }
  } else {
    // q = c + FV@f + F^T v , rows (b-55)*256 + tid
    int i = (b - 55) * 256 + tid;
    if (i < DIM) {
      float acc = cvec[i];
      const float4* fr4 = (const float4*)(FV + (size_t)i * N_ST);
      const float4* f4 = (const float4*)f;
      float a4 = 0.0f;
      for (int kk = 0; kk < N_ST/4; kk++) {
        float4 x = fr4[kk], y = f4[kk];
        a4 += x.x*y.x + x.y*y.y + x.z*y.z + x.w*y.w;
      }
      float a2 = 0.0f;
      for (int k = 0; k < N_ST; k++)
        a2 += F[(size_t)k*DIM + i] * vin[k];
      qv[i] = acc + a4 + a2;
    }
  }
}

// ---------------------------------------------------------------------------
// TRSM: per column j (0..511 = Qux cols, 512 = qu): forward L w = b -> Wt
// row j (and wv); backward L^T y = w -> K (and k). Unchanged this round.
// ---------------------------------------------------------------------------
__global__ __launch_bounds__(256) void trsm_kernel(
    const float* __restrict__ Lw,
    const float* __restrict__ invd,
    const float* __restrict__ Qm,
    const float* __restrict__ qv,
    float* __restrict__ Wt,
    ushort* __restrict__ Wth,
    ushort* __restrict__ Wtl,
    float* __restrict__ wv,
    float* __restrict__ kv,
    float* __restrict__ outK,
    float* __restrict__ outks)
{
  __shared__ float Lp[LTRI];
  __shared__ float di[128];
  const int tid = threadIdx.x;
  for (int idx = tid; idx < LTRI; idx += 256) Lp[idx] = Lw[idx];
  if (tid < 128) di[tid] = invd[tid];
  __syncthreads();

  const int wvid = tid >> 6, lane = tid & 63;
  const int j = blockIdx.x * 4 + wvid;
  if (j > N_ST) return;

  float b0, b1;
  if (j < N_ST) {
    b0 = Qm[(size_t)(N_ST + lane)*DIM + j];
    b1 = Qm[(size_t)(N_ST + 64 + lane)*DIM + j];
  } else {
    b0 = qv[N_ST + lane];
    b1 = qv[N_ST + 64 + lane];
  }

  float x0 = 0.0f, x1 = 0.0f;
  int uoff = 0;
  for (int u = 0; u < 128; u++) {
    float s = Lp[uoff + lane]*x0 + Lp[uoff + 64 + lane]*x1;
#pragma unroll
    for (int off = 32; off > 0; off >>= 1) s += __shfl_xor(s, off);
    float bu = (u < 64) ? __shfl(b0, u) : __shfl(b1, u - 64);
    float wu = (bu - s) * di[u];
    if (u < 64) { if (lane == u)      x0 = wu; }
    else        { if (lane == u - 64) x1 = wu; }
    uoff += u + 1;
  }
  if (j < N_ST) {
    size_t o = (size_t)j * N_CT;
    Wt[o + lane] = x0; Wt[o + 64 + lane] = x1;
    ushort h0 = f2bf(x0), h1 = f2bf(x1);
    Wth[o + lane] = h0;      Wtl[o + lane] = f2bf(x0 - bf2f(h0));
    Wth[o + 64 + lane] = h1; Wtl[o + 64 + lane] = f2bf(x1 - bf2f(h1));
  } else {
    wv[lane] = x0; wv[64 + lane] = x1;
  }

  const int toff0 = lane*(lane + 1)/2;
  const int toff1 = (64 + lane)*(65 + lane)/2;
  float y0 = 0.0f, y1 = 0.0f;
  for (int u = 127; u >= 0; u--) {
    float s = Lp[toff0 + u]*y0 + Lp[toff1 + u]*y1;
#pragma unroll
    for (int off = 32; off > 0; off >>= 1) s += __shfl_xor(s, off);
    float wu2 = (u < 64) ? __shfl(x0, u) : __shfl(x1, u - 64);
    float yu = (wu2 - s) * di[u];
    if (u < 64) { if (lane == u)      y0 = yu; }
    else        { if (lane == u - 64) y1 = yu; }
  }
  if (j < N_ST) {
    outK[(size_t)lane*N_ST + j]        = -y0;
    outK[(size_t)(64 + lane)*N_ST + j] = -y1;
  } else {
    kv[lane] = -y0; kv[64 + lane] = -y1;
    outks[lane] = -y0; outks[64 + lane] = -y1;
  }
}

// ---------------------------------------------------------------------------
// Kernel 4: Vn = Qxx - Wt Wt^T, lower tiles only (36 blocks) + mirror,
// split bf16 out. Blocks 36,37: vn = qx - Wt@wv. Block 38: const.
// ---------------------------------------------------------------------------
__global__ __launch_bounds__(256) void gemm_vn_kernel(
    const ushort* __restrict__ Wth, const ushort* __restrict__ Wtl,
    const float* __restrict__ Qm,
    float* __restrict__ outV, ushort* __restrict__ Vh, ushort* __restrict__ Vl,
    const float* __restrict__ qv, const float* __restrict__ Wt,
    const float* __restrict__ wv, const float* __restrict__ kv,
    const float* __restrict__ Vf, const float* __restrict__ fv,
    const float* __restrict__ f, const float* __restrict__ constp,
    float* __restrict__ outv, float* __restrict__ outc, float* __restrict__ wsconst)
{
  __shared__ ushort As_h[64*72], As_l[64*72], Bs_h[64*72], Bs_l[64*72];
  __shared__ float red[256];
  const int b = blockIdx.x, tid = threadIdx.x;

  if (b < 36) {
    int bi, bj; tri_decode(b, bi, bj);      // 8x8 lower
    const int i0 = bi * 64, j0 = bj * 64;
    f32x4 acc[2][2];
    gemm_core(Wth, Wtl, N_CT, Wth, Wtl, N_CT, i0, j0, N_CT,
              As_h, As_l, Bs_h, Bs_l, acc);
    const int wid = tid >> 6, lane = tid & 63;
    const int wm = (wid & 1)*32, wn = (wid >> 1)*32;
    const int fr = lane & 15, fq = lane >> 4;
#pragma unroll
    for (int tm = 0; tm < 2; tm++)
#pragma unroll
      for (int tn = 0; tn < 2; tn++)
#pragma unroll
        for (int r = 0; r < 4; r++) {
          int i = i0 + wm + tm*16 + fq*4 + r;
          int j = j0 + wn + tn*16 + fr;
          float v = Qm[(size_t)i*DIM + j] - acc[tm][tn][r];
          ushort h = f2bf(v);
          ushort l = f2bf(v - bf2f(h));
          size_t o = (size_t)i * N_ST + j;
          outV[o] = v; Vh[o] = h; Vl[o] = l;
          if (bi != bj) {
            size_t om = (size_t)j * N_ST + i;
            outV[om] = v; Vh[om] = h; Vl[om] = l;
          }
        }
  } else if (b < 38) {
    int i = (b - 36) * 256 + tid;
    const float4* wr = (const float4*)(Wt + (size_t)i * N_CT);
    const float4* w4 = (const float4*)wv;
    float acc = 0.0f;
    for (int u = 0; u < N_CT/4; u++) {
      float4 x = wr[u], y = w4[u];
      acc += x.x*y.x + x.y*y.y + x.z*y.z + x.w*y.w;
    }
    outv[i] = qv[i] - acc;
  } else {
    float pv = 0.0f;
    if (tid < 128) {
      float qk = 0.0f;
      for (int u = 0; u < 128; u++)
        qk += Qm[(size_t)(N_ST + tid)*DIM + N_ST + u] * kv[u];
      pv = kv[tid] * (0.5f*qk + qv[N_ST + tid]);
      float fa = 0.0f;
#pragma unroll
      for (int r = 0; r < 4; r++) { int jj = tid*4 + r; fa += f[jj] * Vf[jj]; }
      pv += 0.5f * fa;
    }
    red[tid] = pv;
    __syncthreads();
    for (int s2 = 128; s2 > 0; s2 >>= 1) {
      if (tid < s2) red[tid] += red[tid + s2];
      __syncthreads();
    }
    if (tid == 0) {
      float cn = constp[0] + red[0] + fv[0];
      outc[0] = cn;
      wsconst[0] = cn;
    }
  }
}

// ---------------------------------------------------------------------------
// FT[i][k] = F[k][i] as bf16 hi/lo (640x512).  Once per launch.
// ---------------------------------------------------------------------------
__global__ __launch_bounds__(256) void convert_FT(
    const float* __restrict__ F, ushort* __restrict__ FTh, ushort* __restrict__ FTl)
{
  __shared__ float tile[32][33];
  const int bi = blockIdx.x, bk = blockIdx.y;
  const int tx = threadIdx.x & 31, ty = threadIdx.x >> 5;
#pragma unroll
  for (int r = 0; r < 4; r++)
    tile[ty + r*8][tx] = F[(size_t)(bk*32 + ty + r*8)*DIM + bi*32 + tx];
  __syncthreads();
#pragma unroll
  for (int r = 0; r < 4; r++) {
    float v = tile[tx][ty + r*8];
    ushort h = f2bf(v);
    size_t o = (size_t)(bi*32 + ty + r*8)*N_ST + bk*32 + tx;
    FTh[o] = h;
    FTl[o] = f2bf(v - bf2f(h));
  }
}

// V0 split from Cm[:512,:512] (ld 640). Once per launch.
__global__ __launch_bounds__(256) void convert_V0(
    const float* __restrict__ Cm, ushort* __restrict__ Vh, ushort* __restrict__ Vl)
{
  int idx = blockIdx.x * 256 + threadIdx.x;
  int i = idx >> 9, j = idx & 511;
  float v = Cm[(size_t)i*DIM + j];
  ushort h = f2bf(v);
  Vh[(size_t)i*N_ST + j] = h;
  Vl[(size_t)i*N_ST + j] = f2bf(v - bf2f(h));
}

// ---------------------------------------------------------------------------
extern "C" void kernel_launch(void* const* d_in, const int* in_sizes, int n_in,
                              void* d_out, int out_size, void* d_ws, size_t ws_size,
                              hipStream_t stream)
{
  (void)in_sizes; (void)n_in; (void)out_size; (void)ws_size;
  const float* F  = (const float*)d_in[0];   // (512, 640)
  const float* f  = (const float*)d_in[1];   // (512,)
  const float* Cm = (const float*)d_in[2];   // (640, 640)
  const float* cv = (const float*)d_in[3];   // (640,)

  float* out   = (float*)d_out;
  float* outK  = out;                                        // T x 128 x 512
  float* outks = outK  + (size_t)T_H * N_CT * N_ST;          // T x 128
  float* outVs = outks + (size_t)T_H * N_CT;                 // T x 512 x 512
  float* outvs = outVs + (size_t)T_H * N_ST * N_ST;          // T x 512
  float* outcs = outvs + (size_t)T_H * N_ST;                 // T

  // workspace layout (float units, every array 256B-aligned)
  float* ws   = (float*)d_ws;
  float* FV   = ws;                          // 640*512
  float* Qm   = FV   + (size_t)DIM * N_ST;   // 640*640
  float* qv   = Qm   + (size_t)DIM * DIM;    // 640
  float* Lw   = qv   + DIM;                  // 8256
  float* invd = Lw   + LTRI;                 // 128
  float* Wt   = invd + 128;                  // 512*128
  float* wv   = Wt   + (size_t)N_ST * N_CT;  // 128
  float* kv   = wv   + 128;                  // 128
  float* Vf   = kv   + 128;                  // 512
  float* fv   = Vf   + N_ST;                 // (pad 64)
  float* cst  = fv   + 64;                   // (pad 64)
  ushort* FTh = (ushort*)(cst + 64);                 // 640*512
  ushort* FTl = FTh + (size_t)DIM * N_ST;            // 640*512
  ushort* Vh  = FTl + (size_t)DIM * N_ST;            // 512*512
  ushort* Vl  = Vh  + (size_t)N_ST * N_ST;           // 512*512
  ushort* FVh = Vl  + (size_t)N_ST * N_ST;           // 640*512
  ushort* FVl = FVh + (size_t)DIM * N_ST;            // 640*512
  ushort* Wth = FVl + (size_t)DIM * N_ST;            // 512*128
  ushort* Wtl = Wth + (size_t)N_ST * N_CT;           // 512*128
  unsigned* cnt = (unsigned*)(Wtl + (size_t)N_ST * N_CT); // 1

  hipMemsetAsync(cst, 0, sizeof(float), stream);
  hipMemsetAsync(cnt, 0, sizeof(unsigned), stream);

  // one-time conversions (cheap, per launch)
  convert_FT<<<dim3(DIM/32, N_ST/32), 256, 0, stream>>>(F, FTh, FTl);
  convert_V0<<<(N_ST*N_ST)/256, 256, 0, stream>>>(Cm, Vh, Vl);

  for (int s = 0; s < T_H; s++) {
    const float* Vin; int ldV; const float* vin;
    if (s == 0) { Vin = Cm; ldV = DIM; vin = cv; }
    else {
      Vin = outVs + (size_t)(T_H - s) * N_ST * N_ST; ldV = N_ST;
      vin = outvs + (size_t)(T_H - s) * N_ST;
    }
    const size_t slot = (size_t)(T_H - 1 - s);

    // FV = F^T V (+ Vf, fv aux)
    gemm_fv_kernel<<<81, 256, 0, stream>>>(
        FTh, FTl, Vh, Vl, FV, FVh, FVl, Vin, ldV, vin, f, Vf, fv);
    // Q = C + FV F (lower tiles + mirror) + Cholesky tail + q aux
    gemm_q_kernel<<<58, 256, 0, stream>>>(
        FVh, FVl, FTh, FTl, Cm, Qm, FV, F, f, cv, vin, qv, Lw, invd, cnt, s);
    // Wt, wv, K, k
    trsm_kernel<<<129, 256, 0, stream>>>(Lw, invd, Qm, qv, Wt, Wth, Wtl,
                                         wv, kv,
                                         outK + slot * N_CT * N_ST,
                                         outks + slot * N_CT);
    // Vn = Qxx - Wt Wt^T (lower tiles + mirror) + vn + const
    gemm_vn_kernel<<<39, 256, 0, stream>>>(
        Wth, Wtl, Qm,
        outVs + slot * N_ST * N_ST, Vh, Vl,
        qv, Wt, wv, kv, Vf, fv, f, cst,
        outvs + slot * N_ST, outcs + slot, cst);
  }
}